// Round 1
// baseline (1329.949 us; speedup 1.0000x reference)
//
#include <hip/hip_runtime.h>
#include <math.h>

#define L_TOK 257
#define N_B 32
#define C_DIM 768
#define N_H 12
#define HD 64
#define BH (N_B * N_H)          /* 384 */
#define M_TOK (L_TOK * N_B)     /* 8224 */
#define HW 256
#define RPE_NUM 33
#define KL 232                  /* kn rows staged in LDS */
#define LOGIT_MAX 4.6051701859880913680f

// ---------------- generic GEMM: C[M][Nn] = A[M][K] @ W[Nn][K]^T + bias ----------------
__global__ __launch_bounds__(256)
void gemm_nt(const float* __restrict__ A, const float* __restrict__ W,
             const float* __restrict__ bias, float* __restrict__ Cout,
             int M, int Nn, int K) {
  __shared__ float As[16][68];
  __shared__ float Bs[16][68];
  const int t = threadIdx.x;
  const int tm = t & 15, tn = t >> 4;
  const int m0 = blockIdx.x * 64, n0 = blockIdx.y * 64;
  const int lr = t >> 2, lc = (t & 3) << 2;
  float acc[4][4] = {};
  for (int k0 = 0; k0 < K; k0 += 16) {
    float4 av = make_float4(0.f, 0.f, 0.f, 0.f);
    float4 wv = make_float4(0.f, 0.f, 0.f, 0.f);
    int gm = m0 + lr;
    if (gm < M) av = *(const float4*)(A + (size_t)gm * K + k0 + lc);
    int gn = n0 + lr;
    if (gn < Nn) wv = *(const float4*)(W + (size_t)gn * K + k0 + lc);
    __syncthreads();
    As[lc + 0][lr] = av.x; As[lc + 1][lr] = av.y; As[lc + 2][lr] = av.z; As[lc + 3][lr] = av.w;
    Bs[lc + 0][lr] = wv.x; Bs[lc + 1][lr] = wv.y; Bs[lc + 2][lr] = wv.z; Bs[lc + 3][lr] = wv.w;
    __syncthreads();
#pragma unroll
    for (int k = 0; k < 16; ++k) {
      float4 a = *(const float4*)&As[k][tm << 2];
      float4 b = *(const float4*)&Bs[k][tn << 2];
      acc[0][0] += a.x * b.x; acc[0][1] += a.x * b.y; acc[0][2] += a.x * b.z; acc[0][3] += a.x * b.w;
      acc[1][0] += a.y * b.x; acc[1][1] += a.y * b.y; acc[1][2] += a.y * b.z; acc[1][3] += a.y * b.w;
      acc[2][0] += a.z * b.x; acc[2][1] += a.z * b.y; acc[2][2] += a.z * b.z; acc[2][3] += a.z * b.w;
      acc[3][0] += a.w * b.x; acc[3][1] += a.w * b.y; acc[3][2] += a.w * b.z; acc[3][3] += a.w * b.w;
    }
  }
  const int gn = n0 + (tn << 2);
  const float4 bv = *(const float4*)(bias + gn);
#pragma unroll
  for (int r = 0; r < 4; ++r) {
    int gm = m0 + (tm << 2) + r;
    if (gm < M) {
      float4 o;
      o.x = acc[r][0] + bv.x; o.y = acc[r][1] + bv.y;
      o.z = acc[r][2] + bv.z; o.w = acc[r][3] + bv.w;
      *(float4*)(Cout + (size_t)gm * Nn + gn) = o;
    }
  }
}

// ---------------- repack qkv -> qn/kn/v in [b][l][64], L2-normalizing q,k ----------------
__global__ __launch_bounds__(256)
void repack_norm(const float* __restrict__ qkv, float* __restrict__ qn,
                 float* __restrict__ kn, float* __restrict__ v) {
  int gw = blockIdx.x * 4 + (threadIdx.x >> 6);
  int lane = threadIdx.x & 63;
  int b = gw / L_TOK, l = gw - b * L_TOK;
  int n = b / N_H, h = b - n * N_H;
  size_t base = (size_t)(l * N_B + n) * (3 * C_DIM) + h * HD + lane;
  float q = qkv[base];
  float k = qkv[base + C_DIM];
  float vv = qkv[base + 2 * C_DIM];
  float sq = q * q, sk = k * k;
#pragma unroll
  for (int o = 32; o > 0; o >>= 1) {
    sq += __shfl_down(sq, o);
    sk += __shfl_down(sk, o);
  }
  sq = __shfl(sq, 0);
  sk = __shfl(sk, 0);
  float iq = 1.0f / fmaxf(sqrtf(sq), 1e-12f);
  float ik = 1.0f / fmaxf(sqrtf(sk), 1e-12f);
  size_t ob = (size_t)(b * L_TOK + l) * HD + lane;
  qn[ob] = q * iq;
  kn[ob] = k * ik;
  v[ob] = vv;
}

// ---------------- attention rows: logits + rpe bias + softmax -> P ----------------
__global__ __launch_bounds__(256)
void attn_rows(const float* __restrict__ qn, const float* __restrict__ kn,
               const float* __restrict__ depth, const float* __restrict__ rpe,
               const float* __restrict__ logit_scale, float* __restrict__ P) {
  __shared__ float kn_s[KL][HD + 1];   // 60,320 B
  __shared__ float cx[HW], cy[HW], cz[HW];
  __shared__ float tbl[3 * RPE_NUM];
  __shared__ float q_s[4][HD];
  __shared__ float red[16];
  const int b = blockIdx.x;
  const int n = b / N_H, h = b - n * N_H;
  const int t = threadIdx.x;
  const int lane = t & 63, wave = t >> 6;

  // depth -> min/max -> coords (bit-exact op sequence vs reference)
  float dval = depth[n * HW + t];
  float mn = dval, mx = dval;
#pragma unroll
  for (int o = 32; o > 0; o >>= 1) {
    mn = fminf(mn, __shfl_down(mn, o));
    mx = fmaxf(mx, __shfl_down(mx, o));
  }
  if (lane == 0) { red[wave] = mn; red[8 + wave] = mx; }
  __syncthreads();
  float zmin = fminf(fminf(red[0], red[1]), fminf(red[2], red[3]));
  float zmax = fmaxf(fmaxf(red[8], red[9]), fmaxf(red[10], red[11]));
  float den = zmax - zmin + 1e-8f;
  cx[t] = (float)(t & 15) / 15.0f;
  cy[t] = (float)(t >> 4) / 15.0f;
  cz[t] = (dval - zmin) / den;
  if (t < 3 * RPE_NUM) tbl[t] = rpe[t * N_H + h];
  const float scale = expf(fminf(logit_scale[h], LOGIT_MAX));

  const float* knb = kn + (size_t)b * L_TOK * HD;
  const float* qb  = qn + (size_t)b * L_TOK * HD;
  float* Pb = P + (size_t)b * L_TOK * L_TOK;
  for (int q4 = t; q4 < KL * (HD / 4); q4 += 256) {
    int j = q4 >> 4, d = (q4 & 15) << 2;
    float4 kv = *(const float4*)(knb + j * HD + d);
    kn_s[j][d] = kv.x; kn_s[j][d + 1] = kv.y; kn_s[j][d + 2] = kv.z; kn_s[j][d + 3] = kv.w;
  }
  __syncthreads();

  for (int i0 = 0; i0 < L_TOK; i0 += 4) {
    const int nr = min(4, L_TOK - i0);
    if (wave < nr) q_s[wave][lane] = qb[(i0 + wave) * HD + lane];
    __syncthreads();

    // --- dot products for key j = t ---
    float la[4] = {0.f, 0.f, 0.f, 0.f};
    const int j = t;
    if (j < KL) {
#pragma unroll
      for (int d = 0; d < HD; ++d) {
        float kv = kn_s[j][d];
        la[0] += kv * q_s[0][d];
        la[1] += kv * q_s[1][d];
        la[2] += kv * q_s[2][d];
        la[3] += kv * q_s[3][d];
      }
    } else {
      const float4* kr = (const float4*)(knb + (size_t)j * HD);
#pragma unroll
      for (int d4 = 0; d4 < HD / 4; ++d4) {
        float4 kv = kr[d4];
        int d = d4 << 2;
        la[0] += kv.x * q_s[0][d] + kv.y * q_s[0][d + 1] + kv.z * q_s[0][d + 2] + kv.w * q_s[0][d + 3];
        la[1] += kv.x * q_s[1][d] + kv.y * q_s[1][d + 1] + kv.z * q_s[1][d + 2] + kv.w * q_s[1][d + 3];
        la[2] += kv.x * q_s[2][d] + kv.y * q_s[2][d + 1] + kv.z * q_s[2][d + 2] + kv.w * q_s[2][d + 3];
        la[3] += kv.x * q_s[3][d] + kv.y * q_s[3][d + 1] + kv.z * q_s[3][d + 2] + kv.w * q_s[3][d + 3];
      }
    }

    // --- bias + scale -> logits for j = t ---
    float lg[4];
    float cxj = 0.f, cyj = 0.f, czj = 0.f;
    if (j >= 1) { cxj = cx[j - 1]; cyj = cy[j - 1]; czj = cz[j - 1]; }
#pragma unroll
    for (int r = 0; r < 4; ++r) {
      int i = i0 + r;
      float bsum = 0.f;
      if (j >= 1 && i >= 1 && i < L_TOK) {
        float rx = (cx[i - 1] - cxj) * 16.0f;
        float ry = (cy[i - 1] - cyj) * 16.0f;
        float rz = (cz[i - 1] - czj) * 16.0f;
        int ix = (int)rintf(rx); ix = max(-16, min(16, ix));
        int iy = (int)rintf(ry); iy = max(-16, min(16, iy));
        int iz = (int)rintf(rz); iz = max(-16, min(16, iz));
        bsum = tbl[ix + 16] + tbl[iy + 16 + RPE_NUM] + tbl[iz + 16 + 2 * RPE_NUM];
      }
      lg[r] = scale * la[r] + bsum;
    }

    // --- key j = 256, computed cooperatively by wave 0 (result on t==0) ---
    float lb[4] = {0.f, 0.f, 0.f, 0.f};
    if (wave == 0) {
      float kv = knb[256 * HD + lane];
      float p0 = kv * q_s[0][lane];
      float p1 = kv * q_s[1][lane];
      float p2 = kv * q_s[2][lane];
      float p3 = kv * q_s[3][lane];
#pragma unroll
      for (int o = 32; o > 0; o >>= 1) {
        p0 += __shfl_down(p0, o);
        p1 += __shfl_down(p1, o);
        p2 += __shfl_down(p2, o);
        p3 += __shfl_down(p3, o);
      }
      if (lane == 0) {
        float cxj2 = cx[255], cyj2 = cy[255], czj2 = cz[255];
        float dts[4] = {p0, p1, p2, p3};
#pragma unroll
        for (int r = 0; r < 4; ++r) {
          int i = i0 + r;
          float bsum = 0.f;
          if (i >= 1 && i < L_TOK) {
            float rx = (cx[i - 1] - cxj2) * 16.0f;
            float ry = (cy[i - 1] - cyj2) * 16.0f;
            float rz = (cz[i - 1] - czj2) * 16.0f;
            int ix = (int)rintf(rx); ix = max(-16, min(16, ix));
            int iy = (int)rintf(ry); iy = max(-16, min(16, iy));
            int iz = (int)rintf(rz); iz = max(-16, min(16, iz));
            bsum = tbl[ix + 16] + tbl[iy + 16 + RPE_NUM] + tbl[iz + 16 + 2 * RPE_NUM];
          }
          lb[r] = scale * dts[r] + bsum;
        }
      }
    }

    // --- block softmax over 257 keys, 4 rows at once ---
    float m[4];
#pragma unroll
    for (int r = 0; r < 4; ++r) m[r] = (t == 0) ? fmaxf(lg[r], lb[r]) : lg[r];
#pragma unroll
    for (int o = 32; o > 0; o >>= 1) {
      m[0] = fmaxf(m[0], __shfl_down(m[0], o));
      m[1] = fmaxf(m[1], __shfl_down(m[1], o));
      m[2] = fmaxf(m[2], __shfl_down(m[2], o));
      m[3] = fmaxf(m[3], __shfl_down(m[3], o));
    }
    if (lane == 0) {
      red[wave * 4 + 0] = m[0]; red[wave * 4 + 1] = m[1];
      red[wave * 4 + 2] = m[2]; red[wave * 4 + 3] = m[3];
    }
    __syncthreads();
    float M4[4];
#pragma unroll
    for (int r = 0; r < 4; ++r)
      M4[r] = fmaxf(fmaxf(red[r], red[4 + r]), fmaxf(red[8 + r], red[12 + r]));
    __syncthreads();

    float e[4], eb[4], s[4];
#pragma unroll
    for (int r = 0; r < 4; ++r) {
      e[r] = __expf(lg[r] - M4[r]);
      eb[r] = (t == 0) ? __expf(lb[r] - M4[r]) : 0.f;
      s[r] = e[r] + eb[r];
    }
#pragma unroll
    for (int o = 32; o > 0; o >>= 1) {
      s[0] += __shfl_down(s[0], o);
      s[1] += __shfl_down(s[1], o);
      s[2] += __shfl_down(s[2], o);
      s[3] += __shfl_down(s[3], o);
    }
    if (lane == 0) {
      red[wave * 4 + 0] = s[0]; red[wave * 4 + 1] = s[1];
      red[wave * 4 + 2] = s[2]; red[wave * 4 + 3] = s[3];
    }
    __syncthreads();
    float S4[4];
#pragma unroll
    for (int r = 0; r < 4; ++r)
      S4[r] = (red[r] + red[4 + r]) + (red[8 + r] + red[12 + r]);

    for (int r = 0; r < nr; ++r) {
      float inv = 1.0f / S4[r];
      Pb[(size_t)(i0 + r) * L_TOK + t] = e[r] * inv;
      if (t == 0) Pb[(size_t)(i0 + r) * L_TOK + 256] = eb[r] * inv;
    }
    __syncthreads();
  }
}

// ---------------- PV: out(L,N,C) = P(257x257) @ V(257x64) per head-batch ----------------
__global__ __launch_bounds__(256)
void pv_gemm(const float* __restrict__ P, const float* __restrict__ v,
             float* __restrict__ out_lnc) {
  __shared__ float Ps[64][65];   // [k][i]
  __shared__ float Vs[64][65];   // [k][d]
  const int b = blockIdx.y;
  const int n = b / N_H, h = b - n * N_H;
  const int i0 = blockIdx.x * 64;
  const int t = threadIdx.x;
  const int tm = t & 15, tn = t >> 4;
  const float* Pb = P + (size_t)b * L_TOK * L_TOK;
  const float* vb = v + (size_t)b * L_TOK * HD;
  float acc[4][4] = {};
  for (int k0 = 0; k0 < L_TOK; k0 += 64) {
    __syncthreads();
#pragma unroll
    for (int p = 0; p < 16; ++p) {
      int idx = p * 256 + t;
      int r = idx >> 6, c = idx & 63;
      float pv = 0.f;
      if (i0 + r < L_TOK && k0 + c < L_TOK)
        pv = Pb[(size_t)(i0 + r) * L_TOK + k0 + c];
      Ps[c][r] = pv;
      float vv = 0.f;
      if (k0 + r < L_TOK) vv = vb[(size_t)(k0 + r) * HD + c];
      Vs[r][c] = vv;
    }
    __syncthreads();
#pragma unroll 16
    for (int k = 0; k < 64; ++k) {
      float a0 = Ps[k][(tm << 2) + 0], a1 = Ps[k][(tm << 2) + 1];
      float a2 = Ps[k][(tm << 2) + 2], a3 = Ps[k][(tm << 2) + 3];
      float b0 = Vs[k][(tn << 2) + 0], b1 = Vs[k][(tn << 2) + 1];
      float b2 = Vs[k][(tn << 2) + 2], b3 = Vs[k][(tn << 2) + 3];
      acc[0][0] += a0 * b0; acc[0][1] += a0 * b1; acc[0][2] += a0 * b2; acc[0][3] += a0 * b3;
      acc[1][0] += a1 * b0; acc[1][1] += a1 * b1; acc[1][2] += a1 * b2; acc[1][3] += a1 * b3;
      acc[2][0] += a2 * b0; acc[2][1] += a2 * b1; acc[2][2] += a2 * b2; acc[2][3] += a2 * b3;
      acc[3][0] += a3 * b0; acc[3][1] += a3 * b1; acc[3][2] += a3 * b2; acc[3][3] += a3 * b3;
    }
  }
#pragma unroll
  for (int r = 0; r < 4; ++r) {
    int i = i0 + (tm << 2) + r;
    if (i < L_TOK) {
      size_t o = ((size_t)i * N_B + n) * C_DIM + h * HD + (tn << 2);
      *(float4*)(out_lnc + o) = make_float4(acc[r][0], acc[r][1], acc[r][2], acc[r][3]);
    }
  }
}

extern "C" void kernel_launch(void* const* d_in, const int* in_sizes, int n_in,
                              void* d_out, int out_size, void* d_ws, size_t ws_size,
                              hipStream_t stream) {
  const float* x      = (const float*)d_in[0];
  const float* depth  = (const float*)d_in[1];
  const float* w_in   = (const float*)d_in[2];
  const float* b_in   = (const float*)d_in[3];
  const float* w_out  = (const float*)d_in[4];
  const float* b_out  = (const float*)d_in[5];
  const float* rpe    = (const float*)d_in[6];
  const float* lscale = (const float*)d_in[7];
  float* out = (float*)d_out;
  float* ws = (float*)d_ws;

  float* qkv      = ws;                       // 8224*2304 = 18,948,096 floats
  float* attn_lnc = ws;                       // reused after repack
  float* qn = ws + 18948096;                  // 384*257*64 = 6,316,032 each
  float* kn = qn + 6316032;
  float* v  = kn + 6316032;
  float* Pout = out + 6316032;                // attn output region

  gemm_nt<<<dim3(129, 36), 256, 0, stream>>>(x, w_in, b_in, qkv, M_TOK, 3 * C_DIM, C_DIM);
  repack_norm<<<24672, 256, 0, stream>>>(qkv, qn, kn, v);
  attn_rows<<<BH, 256, 0, stream>>>(qn, kn, depth, rpe, lscale, Pout);
  pv_gemm<<<dim3(5, BH), 256, 0, stream>>>(Pout, v, attn_lnc);
  gemm_nt<<<dim3(129, 12), 256, 0, stream>>>(attn_lnc, w_out, b_out, out, M_TOK, C_DIM, C_DIM);
}

// Round 2
// 899.884 us; speedup vs baseline: 1.4779x; 1.4779x over previous
//
#include <hip/hip_runtime.h>
#include <math.h>

#define L_TOK 257
#define N_B 32
#define C_DIM 768
#define N_H 12
#define HD 64
#define BH (N_B * N_H)          /* 384 */
#define M_TOK (L_TOK * N_B)     /* 8224 */
#define HW 256
#define RPE_NUM 33
#define KL 232                  /* kn rows staged in LDS */
#define LOGIT_MAX 4.6051701859880913680f

typedef unsigned short ushort;
typedef unsigned int uint;
typedef __attribute__((ext_vector_type(8))) short short8;
typedef __attribute__((ext_vector_type(4))) float f32x4;

__device__ __forceinline__ ushort f2bf_rn(float f) {
  uint u = __float_as_uint(f);
  uint r = (u + 0x7FFF + ((u >> 16) & 1)) >> 16;
  return (ushort)r;
}
__device__ __forceinline__ float bf2f(ushort h) {
  return __uint_as_float(((uint)h) << 16);
}

// ---------------- fp32 -> bf16 hi/lo split ----------------
__global__ __launch_bounds__(256)
void cvt_split(const float* __restrict__ src, ushort* __restrict__ hi,
               ushort* __restrict__ lo, int n) {
  int i = (blockIdx.x * 256 + threadIdx.x) * 4;
  if (i + 3 >= n + 3) return;
  if (i + 3 < n) {
    float4 v = *(const float4*)(src + i);
    ushort h0 = f2bf_rn(v.x), h1 = f2bf_rn(v.y), h2 = f2bf_rn(v.z), h3 = f2bf_rn(v.w);
    ushort l0 = f2bf_rn(v.x - bf2f(h0)), l1 = f2bf_rn(v.y - bf2f(h1));
    ushort l2 = f2bf_rn(v.z - bf2f(h2)), l3 = f2bf_rn(v.w - bf2f(h3));
    *(ushort4*)(hi + i) = make_ushort4(h0, h1, h2, h3);
    *(ushort4*)(lo + i) = make_ushort4(l0, l1, l2, l3);
  } else {
    for (int k = i; k < n; ++k) {
      float vv = src[k];
      ushort h = f2bf_rn(vv);
      hi[k] = h; lo[k] = f2bf_rn(vv - bf2f(h));
    }
  }
}

// ---------------- split-bf16 MFMA GEMM: C[M][Nn] = A[M][K] @ W[Nn][K]^T + bias ----------------
// A given as Ahi/Alo bf16, W as Bhi/Blo bf16. 3-product split for fp32-class accuracy.
__global__ __launch_bounds__(256)
void gemm_mfma_split(const ushort* __restrict__ Ahi, const ushort* __restrict__ Alo,
                     const ushort* __restrict__ Bhi, const ushort* __restrict__ Blo,
                     const float* __restrict__ bias, float* __restrict__ Cout,
                     int M, int Nn, int K) {
  __shared__ __align__(16) ushort lds[4 * 128 * 32];   // 32 KB
  ushort* sAh = lds;
  ushort* sAl = lds + 4096;
  ushort* sBh = lds + 8192;
  ushort* sBl = lds + 12288;

  const int t = threadIdx.x;
  const int wave = t >> 6, lane = t & 63;
  const int wm = (wave & 1) * 64;
  const int wn = (wave >> 1) * 64;
  const int m0 = blockIdx.x * 128;
  const int n0 = blockIdx.y * 128;

  const int ar = t >> 2;            // staging row 0..63 (+half*64)
  const int ac = (t & 3) * 8;       // staging col (ushort)
  const uint ldsOff = (uint)(t & 192) * 16;  // wave*1024 bytes

  const int frm = lane & 15;
  const int frk = (lane >> 4) * 8;

  f32x4 acc[4][4] = {};

  for (int k0 = 0; k0 < K; k0 += 32) {
#pragma unroll
    for (int half = 0; half < 2; ++half) {
      int rA = m0 + half * 64 + ar; if (rA > M - 1) rA = M - 1;
      int rB = n0 + half * 64 + ar;
      size_t gA = (size_t)rA * K + k0 + ac;
      size_t gB = (size_t)rB * K + k0 + ac;
      uint so = (uint)half * 4096 + ldsOff;
      __builtin_amdgcn_global_load_lds(
          (const __attribute__((address_space(1))) void*)(Ahi + gA),
          (__attribute__((address_space(3))) void*)((char*)sAh + so), 16, 0, 0);
      __builtin_amdgcn_global_load_lds(
          (const __attribute__((address_space(1))) void*)(Alo + gA),
          (__attribute__((address_space(3))) void*)((char*)sAl + so), 16, 0, 0);
      __builtin_amdgcn_global_load_lds(
          (const __attribute__((address_space(1))) void*)(Bhi + gB),
          (__attribute__((address_space(3))) void*)((char*)sBh + so), 16, 0, 0);
      __builtin_amdgcn_global_load_lds(
          (const __attribute__((address_space(1))) void*)(Blo + gB),
          (__attribute__((address_space(3))) void*)((char*)sBl + so), 16, 0, 0);
    }
    __syncthreads();   // drains vmcnt(0) then barrier

    short8 ah[4], al[4], bh[4], bl[4];
#pragma unroll
    for (int i = 0; i < 4; ++i) {
      int r = wm + i * 16 + frm;
      ah[i] = *(const short8*)(sAh + r * 32 + frk);
      al[i] = *(const short8*)(sAl + r * 32 + frk);
      int c = wn + i * 16 + frm;
      bh[i] = *(const short8*)(sBh + c * 32 + frk);
      bl[i] = *(const short8*)(sBl + c * 32 + frk);
    }
#pragma unroll
    for (int i = 0; i < 4; ++i)
#pragma unroll
      for (int j = 0; j < 4; ++j) {
        acc[i][j] = __builtin_amdgcn_mfma_f32_16x16x32_bf16(ah[i], bh[j], acc[i][j], 0, 0, 0);
        acc[i][j] = __builtin_amdgcn_mfma_f32_16x16x32_bf16(ah[i], bl[j], acc[i][j], 0, 0, 0);
        acc[i][j] = __builtin_amdgcn_mfma_f32_16x16x32_bf16(al[i], bh[j], acc[i][j], 0, 0, 0);
      }
    __syncthreads();   // protect LDS before next staging
  }

  // epilogue: C/D layout col=lane&15, row=(lane>>4)*4+reg
  const int erow = (lane >> 4) * 2;   // *4 / 2 below
  const int ecol = lane & 15;
#pragma unroll
  for (int j = 0; j < 4; ++j) {
    int col = n0 + wn + j * 16 + ecol;
    float bv = bias[col];
#pragma unroll
    for (int i = 0; i < 4; ++i) {
      int rbase = m0 + wm + i * 16 + (lane >> 4) * 4;
#pragma unroll
      for (int r = 0; r < 4; ++r) {
        int row = rbase + r;
        if (row < M) Cout[(size_t)row * Nn + col] = acc[i][j][r] + bv;
      }
    }
  }
  (void)erow;
}

// ---------------- repack qkv -> qn/kn/v in [b][l][64], L2-normalizing q,k ----------------
__global__ __launch_bounds__(256)
void repack_norm(const float* __restrict__ qkv, float* __restrict__ qn,
                 float* __restrict__ kn, float* __restrict__ v) {
  int gw = blockIdx.x * 4 + (threadIdx.x >> 6);
  int lane = threadIdx.x & 63;
  int b = gw / L_TOK, l = gw - b * L_TOK;
  int n = b / N_H, h = b - n * N_H;
  size_t base = (size_t)(l * N_B + n) * (3 * C_DIM) + h * HD + lane;
  float q = qkv[base];
  float k = qkv[base + C_DIM];
  float vv = qkv[base + 2 * C_DIM];
  float sq = q * q, sk = k * k;
#pragma unroll
  for (int o = 32; o > 0; o >>= 1) {
    sq += __shfl_down(sq, o);
    sk += __shfl_down(sk, o);
  }
  sq = __shfl(sq, 0);
  sk = __shfl(sk, 0);
  float iq = 1.0f / fmaxf(sqrtf(sq), 1e-12f);
  float ik = 1.0f / fmaxf(sqrtf(sk), 1e-12f);
  size_t ob = (size_t)(b * L_TOK + l) * HD + lane;
  qn[ob] = q * iq;
  kn[ob] = k * ik;
  v[ob] = vv;
}

// ---------------- attention rows: logits + rpe bias + softmax -> P ----------------
__global__ __launch_bounds__(256)
void attn_rows(const float* __restrict__ qn, const float* __restrict__ kn,
               const float* __restrict__ depth, const float* __restrict__ rpe,
               const float* __restrict__ logit_scale, float* __restrict__ P) {
  __shared__ float kn_s[KL][HD + 1];   // 60,320 B
  __shared__ float cx[HW], cy[HW], cz[HW];
  __shared__ float tbl[3 * RPE_NUM];
  __shared__ float q_s[4][HD];
  __shared__ float red[16];
  const int b = blockIdx.x;
  const int n = b / N_H, h = b - n * N_H;
  const int t = threadIdx.x;
  const int lane = t & 63, wave = t >> 6;

  float dval = depth[n * HW + t];
  float mn = dval, mx = dval;
#pragma unroll
  for (int o = 32; o > 0; o >>= 1) {
    mn = fminf(mn, __shfl_down(mn, o));
    mx = fmaxf(mx, __shfl_down(mx, o));
  }
  if (lane == 0) { red[wave] = mn; red[8 + wave] = mx; }
  __syncthreads();
  float zmin = fminf(fminf(red[0], red[1]), fminf(red[2], red[3]));
  float zmax = fmaxf(fmaxf(red[8], red[9]), fmaxf(red[10], red[11]));
  float den = zmax - zmin + 1e-8f;
  cx[t] = (float)(t & 15) / 15.0f;
  cy[t] = (float)(t >> 4) / 15.0f;
  cz[t] = (dval - zmin) / den;
  if (t < 3 * RPE_NUM) tbl[t] = rpe[t * N_H + h];
  const float scale = expf(fminf(logit_scale[h], LOGIT_MAX));

  const float* knb = kn + (size_t)b * L_TOK * HD;
  const float* qb  = qn + (size_t)b * L_TOK * HD;
  float* Pb = P + (size_t)b * L_TOK * L_TOK;
  for (int q4 = t; q4 < KL * (HD / 4); q4 += 256) {
    int j = q4 >> 4, d = (q4 & 15) << 2;
    float4 kv = *(const float4*)(knb + j * HD + d);
    kn_s[j][d] = kv.x; kn_s[j][d + 1] = kv.y; kn_s[j][d + 2] = kv.z; kn_s[j][d + 3] = kv.w;
  }
  __syncthreads();

  for (int i0 = 0; i0 < L_TOK; i0 += 4) {
    const int nr = min(4, L_TOK - i0);
    if (wave < nr) q_s[wave][lane] = qb[(i0 + wave) * HD + lane];
    __syncthreads();

    float la[4] = {0.f, 0.f, 0.f, 0.f};
    const int j = t;
    if (j < KL) {
#pragma unroll
      for (int d = 0; d < HD; ++d) {
        float kv = kn_s[j][d];
        la[0] += kv * q_s[0][d];
        la[1] += kv * q_s[1][d];
        la[2] += kv * q_s[2][d];
        la[3] += kv * q_s[3][d];
      }
    } else {
      const float4* kr = (const float4*)(knb + (size_t)j * HD);
#pragma unroll
      for (int d4 = 0; d4 < HD / 4; ++d4) {
        float4 kv = kr[d4];
        int d = d4 << 2;
        la[0] += kv.x * q_s[0][d] + kv.y * q_s[0][d + 1] + kv.z * q_s[0][d + 2] + kv.w * q_s[0][d + 3];
        la[1] += kv.x * q_s[1][d] + kv.y * q_s[1][d + 1] + kv.z * q_s[1][d + 2] + kv.w * q_s[1][d + 3];
        la[2] += kv.x * q_s[2][d] + kv.y * q_s[2][d + 1] + kv.z * q_s[2][d + 2] + kv.w * q_s[2][d + 3];
        la[3] += kv.x * q_s[3][d] + kv.y * q_s[3][d + 1] + kv.z * q_s[3][d + 2] + kv.w * q_s[3][d + 3];
      }
    }

    float lg[4];
    float cxj = 0.f, cyj = 0.f, czj = 0.f;
    if (j >= 1) { cxj = cx[j - 1]; cyj = cy[j - 1]; czj = cz[j - 1]; }
#pragma unroll
    for (int r = 0; r < 4; ++r) {
      int i = i0 + r;
      float bsum = 0.f;
      if (j >= 1 && i >= 1 && i < L_TOK) {
        float rx = (cx[i - 1] - cxj) * 16.0f;
        float ry = (cy[i - 1] - cyj) * 16.0f;
        float rz = (cz[i - 1] - czj) * 16.0f;
        int ix = (int)rintf(rx); ix = max(-16, min(16, ix));
        int iy = (int)rintf(ry); iy = max(-16, min(16, iy));
        int iz = (int)rintf(rz); iz = max(-16, min(16, iz));
        bsum = tbl[ix + 16] + tbl[iy + 16 + RPE_NUM] + tbl[iz + 16 + 2 * RPE_NUM];
      }
      lg[r] = scale * la[r] + bsum;
    }

    float lb[4] = {0.f, 0.f, 0.f, 0.f};
    if (wave == 0) {
      float kv = knb[256 * HD + lane];
      float p0 = kv * q_s[0][lane];
      float p1 = kv * q_s[1][lane];
      float p2 = kv * q_s[2][lane];
      float p3 = kv * q_s[3][lane];
#pragma unroll
      for (int o = 32; o > 0; o >>= 1) {
        p0 += __shfl_down(p0, o);
        p1 += __shfl_down(p1, o);
        p2 += __shfl_down(p2, o);
        p3 += __shfl_down(p3, o);
      }
      if (lane == 0) {
        float cxj2 = cx[255], cyj2 = cy[255], czj2 = cz[255];
        float dts[4] = {p0, p1, p2, p3};
#pragma unroll
        for (int r = 0; r < 4; ++r) {
          int i = i0 + r;
          float bsum = 0.f;
          if (i >= 1 && i < L_TOK) {
            float rx = (cx[i - 1] - cxj2) * 16.0f;
            float ry = (cy[i - 1] - cyj2) * 16.0f;
            float rz = (cz[i - 1] - czj2) * 16.0f;
            int ix = (int)rintf(rx); ix = max(-16, min(16, ix));
            int iy = (int)rintf(ry); iy = max(-16, min(16, iy));
            int iz = (int)rintf(rz); iz = max(-16, min(16, iz));
            bsum = tbl[ix + 16] + tbl[iy + 16 + RPE_NUM] + tbl[iz + 16 + 2 * RPE_NUM];
          }
          lb[r] = scale * dts[r] + bsum;
        }
      }
    }

    float m[4];
#pragma unroll
    for (int r = 0; r < 4; ++r) m[r] = (t == 0) ? fmaxf(lg[r], lb[r]) : lg[r];
#pragma unroll
    for (int o = 32; o > 0; o >>= 1) {
      m[0] = fmaxf(m[0], __shfl_down(m[0], o));
      m[1] = fmaxf(m[1], __shfl_down(m[1], o));
      m[2] = fmaxf(m[2], __shfl_down(m[2], o));
      m[3] = fmaxf(m[3], __shfl_down(m[3], o));
    }
    if (lane == 0) {
      red[wave * 4 + 0] = m[0]; red[wave * 4 + 1] = m[1];
      red[wave * 4 + 2] = m[2]; red[wave * 4 + 3] = m[3];
    }
    __syncthreads();
    float M4[4];
#pragma unroll
    for (int r = 0; r < 4; ++r)
      M4[r] = fmaxf(fmaxf(red[r], red[4 + r]), fmaxf(red[8 + r], red[12 + r]));
    __syncthreads();

    float e[4], eb[4], s[4];
#pragma unroll
    for (int r = 0; r < 4; ++r) {
      e[r] = __expf(lg[r] - M4[r]);
      eb[r] = (t == 0) ? __expf(lb[r] - M4[r]) : 0.f;
      s[r] = e[r] + eb[r];
    }
#pragma unroll
    for (int o = 32; o > 0; o >>= 1) {
      s[0] += __shfl_down(s[0], o);
      s[1] += __shfl_down(s[1], o);
      s[2] += __shfl_down(s[2], o);
      s[3] += __shfl_down(s[3], o);
    }
    if (lane == 0) {
      red[wave * 4 + 0] = s[0]; red[wave * 4 + 1] = s[1];
      red[wave * 4 + 2] = s[2]; red[wave * 4 + 3] = s[3];
    }
    __syncthreads();
    float S4[4];
#pragma unroll
    for (int r = 0; r < 4; ++r)
      S4[r] = (red[r] + red[4 + r]) + (red[8 + r] + red[12 + r]);

    for (int r = 0; r < nr; ++r) {
      float inv = 1.0f / S4[r];
      Pb[(size_t)(i0 + r) * L_TOK + t] = e[r] * inv;
      if (t == 0) Pb[(size_t)(i0 + r) * L_TOK + 256] = eb[r] * inv;
    }
    __syncthreads();
  }
}

// ---------------- PV: out(L,N,C) = P(257x257) @ V(257x64) per head-batch ----------------
__global__ __launch_bounds__(256)
void pv_gemm(const float* __restrict__ P, const float* __restrict__ v,
             float* __restrict__ out_lnc) {
  __shared__ float Ps[64][65];
  __shared__ float Vs[64][65];
  const int b = blockIdx.y;
  const int n = b / N_H, h = b - n * N_H;
  const int i0 = blockIdx.x * 64;
  const int t = threadIdx.x;
  const int tm = t & 15, tn = t >> 4;
  const float* Pb = P + (size_t)b * L_TOK * L_TOK;
  const float* vb = v + (size_t)b * L_TOK * HD;
  float acc[4][4] = {};
  for (int k0 = 0; k0 < L_TOK; k0 += 64) {
    __syncthreads();
#pragma unroll
    for (int p = 0; p < 16; ++p) {
      int idx = p * 256 + t;
      int r = idx >> 6, c = idx & 63;
      float pv = 0.f;
      if (i0 + r < L_TOK && k0 + c < L_TOK)
        pv = Pb[(size_t)(i0 + r) * L_TOK + k0 + c];
      Ps[c][r] = pv;
      float vv = 0.f;
      if (k0 + r < L_TOK) vv = vb[(size_t)(k0 + r) * HD + c];
      Vs[r][c] = vv;
    }
    __syncthreads();
#pragma unroll 16
    for (int k = 0; k < 64; ++k) {
      float a0 = Ps[k][(tm << 2) + 0], a1 = Ps[k][(tm << 2) + 1];
      float a2 = Ps[k][(tm << 2) + 2], a3 = Ps[k][(tm << 2) + 3];
      float b0 = Vs[k][(tn << 2) + 0], b1 = Vs[k][(tn << 2) + 1];
      float b2 = Vs[k][(tn << 2) + 2], b3 = Vs[k][(tn << 2) + 3];
      acc[0][0] += a0 * b0; acc[0][1] += a0 * b1; acc[0][2] += a0 * b2; acc[0][3] += a0 * b3;
      acc[1][0] += a1 * b0; acc[1][1] += a1 * b1; acc[1][2] += a1 * b2; acc[1][3] += a1 * b3;
      acc[2][0] += a2 * b0; acc[2][1] += a2 * b1; acc[2][2] += a2 * b2; acc[2][3] += a2 * b3;
      acc[3][0] += a3 * b0; acc[3][1] += a3 * b1; acc[3][2] += a3 * b2; acc[3][3] += a3 * b3;
    }
  }
#pragma unroll
  for (int r = 0; r < 4; ++r) {
    int i = i0 + (tm << 2) + r;
    if (i < L_TOK) {
      size_t o = ((size_t)i * N_B + n) * C_DIM + h * HD + (tn << 2);
      *(float4*)(out_lnc + o) = make_float4(acc[r][0], acc[r][1], acc[r][2], acc[r][3]);
    }
  }
}

extern "C" void kernel_launch(void* const* d_in, const int* in_sizes, int n_in,
                              void* d_out, int out_size, void* d_ws, size_t ws_size,
                              hipStream_t stream) {
  const float* x      = (const float*)d_in[0];
  const float* depth  = (const float*)d_in[1];
  const float* w_in   = (const float*)d_in[2];
  const float* b_in   = (const float*)d_in[3];
  const float* w_out  = (const float*)d_in[4];
  const float* b_out  = (const float*)d_in[5];
  const float* rpe    = (const float*)d_in[6];
  const float* lscale = (const float*)d_in[7];
  float* out = (float*)d_out;
  float* ws = (float*)d_ws;

  float* qkv      = ws;                        // 18,948,096 floats
  float* attn_lnc = ws;                        // reused (first 6.3M floats)
  float* qn = ws + 18948096;                   // 6,316,032 each
  float* kn = qn + 6316032;
  float* v  = kn + 6316032;
  ushort* wsp = (ushort*)(v + 6316032);
  ushort* wihi = wsp;                          // 1,769,472
  ushort* wilo = wihi + 1769472;
  ushort* wohi = wilo + 1769472;               // 589,824
  ushort* wolo = wohi + 589824;
  ushort* xhi = (ushort*)qn;                   // overlay: dead before repack writes qn
  ushort* xlo = xhi + 6316032;
  ushort* ahi = (ushort*)(qkv + 6316032);      // overlay in qkv region past attn_lnc
  ushort* alo = ahi + 6316032;
  float* Pout = out + 6316032;

  cvt_split<<<6168, 256, 0, stream>>>(x, xhi, xlo, 6316032);
  cvt_split<<<1728, 256, 0, stream>>>(w_in, wihi, wilo, 1769472);
  cvt_split<<<576, 256, 0, stream>>>(w_out, wohi, wolo, 589824);

  gemm_mfma_split<<<dim3(65, 18), 256, 0, stream>>>(xhi, xlo, wihi, wilo, b_in, qkv,
                                                    M_TOK, 3 * C_DIM, C_DIM);
  repack_norm<<<24672, 256, 0, stream>>>(qkv, qn, kn, v);
  attn_rows<<<BH, 256, 0, stream>>>(qn, kn, depth, rpe, lscale, Pout);
  pv_gemm<<<dim3(5, BH), 256, 0, stream>>>(Pout, v, attn_lnc);

  cvt_split<<<6168, 256, 0, stream>>>(attn_lnc, ahi, alo, 6316032);
  gemm_mfma_split<<<dim3(65, 6), 256, 0, stream>>>(ahi, alo, wohi, wolo, b_out, out,
                                                   M_TOK, C_DIM, C_DIM);
}

// Round 3
// 823.763 us; speedup vs baseline: 1.6145x; 1.0924x over previous
//
#include <hip/hip_runtime.h>
#include <math.h>

#define L_TOK 257
#define N_B 32
#define C_DIM 768
#define N_H 12
#define HD 64
#define BH (N_B * N_H)          /* 384 */
#define M_TOK (L_TOK * N_B)     /* 8224 */
#define HW 256
#define RPE_NUM 33
#define LOGIT_MAX 4.6051701859880913680f

typedef unsigned short ushort;
typedef unsigned int uint;
typedef __attribute__((ext_vector_type(8))) short short8;
typedef __attribute__((ext_vector_type(4))) float f32x4;

__device__ __forceinline__ ushort f2bf_rn(float f) {
  uint u = __float_as_uint(f);
  uint r = (u + 0x7FFF + ((u >> 16) & 1)) >> 16;
  return (ushort)r;
}
__device__ __forceinline__ float bf2f(ushort h) {
  return __uint_as_float(((uint)h) << 16);
}

// ---------------- fp32 -> bf16 hi/lo split ----------------
__global__ __launch_bounds__(256)
void cvt_split(const float* __restrict__ src, ushort* __restrict__ hi,
               ushort* __restrict__ lo, int n) {
  int i = (blockIdx.x * 256 + threadIdx.x) * 4;
  if (i + 3 >= n + 3) return;
  if (i + 3 < n) {
    float4 v = *(const float4*)(src + i);
    ushort h0 = f2bf_rn(v.x), h1 = f2bf_rn(v.y), h2 = f2bf_rn(v.z), h3 = f2bf_rn(v.w);
    ushort l0 = f2bf_rn(v.x - bf2f(h0)), l1 = f2bf_rn(v.y - bf2f(h1));
    ushort l2 = f2bf_rn(v.z - bf2f(h2)), l3 = f2bf_rn(v.w - bf2f(h3));
    *(ushort4*)(hi + i) = make_ushort4(h0, h1, h2, h3);
    *(ushort4*)(lo + i) = make_ushort4(l0, l1, l2, l3);
  } else {
    for (int k = i; k < n; ++k) {
      float vv = src[k];
      ushort h = f2bf_rn(vv);
      hi[k] = h; lo[k] = f2bf_rn(vv - bf2f(h));
    }
  }
}

// ---------------- split-bf16 MFMA GEMM: C[M][Nn] = A[M][K] @ W[Nn][K]^T + bias ----------------
__global__ __launch_bounds__(256)
void gemm_mfma_split(const ushort* __restrict__ Ahi, const ushort* __restrict__ Alo,
                     const ushort* __restrict__ Bhi, const ushort* __restrict__ Blo,
                     const float* __restrict__ bias, float* __restrict__ Cout,
                     int M, int Nn, int K) {
  __shared__ __align__(16) ushort lds[4 * 128 * 32];   // 32 KB
  ushort* sAh = lds;
  ushort* sAl = lds + 4096;
  ushort* sBh = lds + 8192;
  ushort* sBl = lds + 12288;

  const int t = threadIdx.x;
  const int wave = t >> 6, lane = t & 63;
  const int wm = (wave & 1) * 64;
  const int wn = (wave >> 1) * 64;
  const int m0 = blockIdx.x * 128;
  const int n0 = blockIdx.y * 128;

  const int ar = t >> 2;
  const int ac = (t & 3) * 8;
  const uint ldsOff = (uint)(t & 192) * 16;

  const int frm = lane & 15;
  const int frk = (lane >> 4) * 8;

  f32x4 acc[4][4] = {};

  for (int k0 = 0; k0 < K; k0 += 32) {
#pragma unroll
    for (int half = 0; half < 2; ++half) {
      int rA = m0 + half * 64 + ar; if (rA > M - 1) rA = M - 1;
      int rB = n0 + half * 64 + ar;
      size_t gA = (size_t)rA * K + k0 + ac;
      size_t gB = (size_t)rB * K + k0 + ac;
      uint so = (uint)half * 4096 + ldsOff;
      __builtin_amdgcn_global_load_lds(
          (const __attribute__((address_space(1))) void*)(Ahi + gA),
          (__attribute__((address_space(3))) void*)((char*)sAh + so), 16, 0, 0);
      __builtin_amdgcn_global_load_lds(
          (const __attribute__((address_space(1))) void*)(Alo + gA),
          (__attribute__((address_space(3))) void*)((char*)sAl + so), 16, 0, 0);
      __builtin_amdgcn_global_load_lds(
          (const __attribute__((address_space(1))) void*)(Bhi + gB),
          (__attribute__((address_space(3))) void*)((char*)sBh + so), 16, 0, 0);
      __builtin_amdgcn_global_load_lds(
          (const __attribute__((address_space(1))) void*)(Blo + gB),
          (__attribute__((address_space(3))) void*)((char*)sBl + so), 16, 0, 0);
    }
    __syncthreads();

    short8 ah[4], al[4], bh[4], bl[4];
#pragma unroll
    for (int i = 0; i < 4; ++i) {
      int r = wm + i * 16 + frm;
      ah[i] = *(const short8*)(sAh + r * 32 + frk);
      al[i] = *(const short8*)(sAl + r * 32 + frk);
      int c = wn + i * 16 + frm;
      bh[i] = *(const short8*)(sBh + c * 32 + frk);
      bl[i] = *(const short8*)(sBl + c * 32 + frk);
    }
#pragma unroll
    for (int i = 0; i < 4; ++i)
#pragma unroll
      for (int j = 0; j < 4; ++j) {
        acc[i][j] = __builtin_amdgcn_mfma_f32_16x16x32_bf16(ah[i], bh[j], acc[i][j], 0, 0, 0);
        acc[i][j] = __builtin_amdgcn_mfma_f32_16x16x32_bf16(ah[i], bl[j], acc[i][j], 0, 0, 0);
        acc[i][j] = __builtin_amdgcn_mfma_f32_16x16x32_bf16(al[i], bh[j], acc[i][j], 0, 0, 0);
      }
    __syncthreads();
  }

  const int ecol = lane & 15;
#pragma unroll
  for (int j = 0; j < 4; ++j) {
    int col = n0 + wn + j * 16 + ecol;
    float bv = bias[col];
#pragma unroll
    for (int i = 0; i < 4; ++i) {
      int rbase = m0 + wm + i * 16 + (lane >> 4) * 4;
#pragma unroll
      for (int r = 0; r < 4; ++r) {
        int row = rbase + r;
        if (row < M) Cout[(size_t)row * Nn + col] = acc[i][j][r] + bv;
      }
    }
  }
}

// ---------------- repack qkv -> qn/kn/v in [b][l][64], L2-normalizing q,k ----------------
__global__ __launch_bounds__(256)
void repack_norm(const float* __restrict__ qkv, float* __restrict__ qn,
                 float* __restrict__ kn, float* __restrict__ v) {
  int gw = blockIdx.x * 4 + (threadIdx.x >> 6);
  int lane = threadIdx.x & 63;
  int b = gw / L_TOK, l = gw - b * L_TOK;
  int n = b / N_H, h = b - n * N_H;
  size_t base = (size_t)(l * N_B + n) * (3 * C_DIM) + h * HD + lane;
  float q = qkv[base];
  float k = qkv[base + C_DIM];
  float vv = qkv[base + 2 * C_DIM];
  float sq = q * q, sk = k * k;
#pragma unroll
  for (int o = 32; o > 0; o >>= 1) {
    sq += __shfl_down(sq, o);
    sk += __shfl_down(sk, o);
  }
  sq = __shfl(sq, 0);
  sk = __shfl(sk, 0);
  float iq = 1.0f / fmaxf(sqrtf(sq), 1e-12f);
  float ik = 1.0f / fmaxf(sqrtf(sk), 1e-12f);
  size_t ob = (size_t)(b * L_TOK + l) * HD + lane;
  qn[ob] = q * iq;
  kn[ob] = k * ik;
  v[ob] = vv;
}

// ---------------- attention rows v2: 4 row-tiles x 384 heads ----------------
// Per block: stage all 257 kn rows in LDS; 8 query rows per pass; Q via
// wave-uniform global loads (s_load); 2 barriers/pass with ping-pong scratch.
__global__ __launch_bounds__(256)
void attn_rows(const float* __restrict__ qn, const float* __restrict__ kn,
               const float* __restrict__ depth, const float* __restrict__ rpe,
               const float* __restrict__ logit_scale, float* __restrict__ P) {
  __shared__ float kn_s[L_TOK * 68];       // 69,904 B, stride 68 (b128 conflict-free)
  __shared__ float cx_s[HW], cy_s[HW], cz_s[HW];
  __shared__ float tbl[3 * RPE_NUM];
  __shared__ float lb_s[2][8];
  __shared__ float redM[2][32];
  __shared__ float redS[2][32];

  const int tile = blockIdx.x;             // 0..3
  const int b = blockIdx.y;
  const int n = b / N_H, h = b - n * N_H;
  const int t = threadIdx.x;
  const int lane = t & 63, wave = t >> 6;

  // ---- coords from depth (bit-exact op sequence vs reference) ----
  float dval = depth[n * HW + t];
  float mn = dval, mx = dval;
#pragma unroll
  for (int o = 32; o > 0; o >>= 1) {
    mn = fminf(mn, __shfl_down(mn, o));
    mx = fmaxf(mx, __shfl_down(mx, o));
  }
  if (lane == 0) { redM[0][wave] = mn; redM[1][wave] = mx; }
  __syncthreads();
  float zmin = fminf(fminf(redM[0][0], redM[0][1]), fminf(redM[0][2], redM[0][3]));
  float zmax = fmaxf(fmaxf(redM[1][0], redM[1][1]), fmaxf(redM[1][2], redM[1][3]));
  float den = zmax - zmin + 1e-8f;
  cx_s[t] = (float)(t & 15) / 15.0f;
  cy_s[t] = (float)(t >> 4) / 15.0f;
  cz_s[t] = (dval - zmin) / den;
  if (t < 3 * RPE_NUM) tbl[t] = rpe[t * N_H + h];
  const float scale = expf(fminf(logit_scale[h], LOGIT_MAX));

  const float* knb = kn + (size_t)b * L_TOK * HD;
  const float* qb  = qn + (size_t)b * L_TOK * HD;
  float* Pb = P + (size_t)b * L_TOK * L_TOK;

  // ---- stage kn (257 x 64 fp32) ----
  for (int idx = t; idx < L_TOK * 16; idx += 256) {
    int row = idx >> 4, c = (idx & 15) << 2;
    float4 kv = *(const float4*)(knb + (size_t)row * HD + c);
    *(float4*)(kn_s + row * 68 + c) = kv;
  }
  __syncthreads();

  // key coords for this thread's key j = t (pass-invariant)
  const bool hasK = (t >= 1);
  float cxk = 0.f, cyk = 0.f, czk = 0.f;
  if (hasK) { cxk = cx_s[t - 1]; cyk = cy_s[t - 1]; czk = cz_s[t - 1]; }
  const float cxK6 = cx_s[255], cyK6 = cy_s[255], czK6 = cz_s[255];

  const int i0 = tile * 64;
  const int nrows = (tile == 3) ? 65 : 64;
  const int npass = (nrows + 7) >> 3;

  for (int p = 0; p < npass; ++p) {
    const int i0r = i0 + (p << 3);
    const int par = p & 1;
    const float* qrow0 = qb + (size_t)i0r * HD;     // wave-uniform base

    // ---- dot products: key t vs 8 query rows ----
    float la[8] = {0.f, 0.f, 0.f, 0.f, 0.f, 0.f, 0.f, 0.f};
#pragma unroll
    for (int d4 = 0; d4 < 16; ++d4) {
      float4 kv = *(const float4*)(kn_s + t * 68 + (d4 << 2));
#pragma unroll
      for (int r = 0; r < 8; ++r) {
        const float* q = qrow0 + r * HD + (d4 << 2);   // uniform -> s_load
        la[r] = fmaf(kv.x, q[0], la[r]);
        la[r] = fmaf(kv.y, q[1], la[r]);
        la[r] = fmaf(kv.z, q[2], la[r]);
        la[r] = fmaf(kv.w, q[3], la[r]);
      }
    }

    // ---- key 256: distributed partial (2 elems/thread, 32-lane reduce) ----
    {
      int r8 = t >> 5;                 // 0..7
      int d0 = (t & 31) << 1;
      float qa = qrow0[r8 * HD + d0];
      float qc = qrow0[r8 * HD + d0 + 1];
      float pp = kn_s[256 * 68 + d0] * qa + kn_s[256 * 68 + d0 + 1] * qc;
#pragma unroll
      for (int o = 16; o > 0; o >>= 1) pp += __shfl_down(pp, o);
      if ((t & 31) == 0) {
        int i = i0r + r8;
        float lg256 = -1e30f;
        if (i < L_TOK) {
          float bsum = 0.f;
          if (i >= 1) {
            float rx = (cx_s[i - 1] - cxK6) * 16.0f;
            float ry = (cy_s[i - 1] - cyK6) * 16.0f;
            float rz = (cz_s[i - 1] - czK6) * 16.0f;
            int ix = (int)rintf(rx); ix = max(-16, min(16, ix));
            int iy = (int)rintf(ry); iy = max(-16, min(16, iy));
            int iz = (int)rintf(rz); iz = max(-16, min(16, iz));
            bsum = tbl[ix + 16] + tbl[iy + 16 + RPE_NUM] + tbl[iz + 16 + 2 * RPE_NUM];
          }
          lg256 = scale * pp + bsum;
        }
        lb_s[par][r8] = lg256;
      }
    }

    // ---- logits with rpe bias ----
    float lg[8];
#pragma unroll
    for (int r = 0; r < 8; ++r) {
      int i = i0r + r;
      float bsum = 0.f;
      if (hasK && i >= 1 && i < L_TOK) {
        float rx = (cx_s[i - 1] - cxk) * 16.0f;
        float ry = (cy_s[i - 1] - cyk) * 16.0f;
        float rz = (cz_s[i - 1] - czk) * 16.0f;
        int ix = (int)rintf(rx); ix = max(-16, min(16, ix));
        int iy = (int)rintf(ry); iy = max(-16, min(16, iy));
        int iz = (int)rintf(rz); iz = max(-16, min(16, iz));
        bsum = tbl[ix + 16] + tbl[iy + 16 + RPE_NUM] + tbl[iz + 16 + 2 * RPE_NUM];
      }
      lg[r] = (i < L_TOK) ? (scale * la[r] + bsum) : -1e30f;
    }

    // ---- block max ----
    float m[8];
#pragma unroll
    for (int r = 0; r < 8; ++r) m[r] = lg[r];
#pragma unroll
    for (int o = 32; o > 0; o >>= 1) {
#pragma unroll
      for (int r = 0; r < 8; ++r) m[r] = fmaxf(m[r], __shfl_down(m[r], o));
    }
    if (lane == 0) {
#pragma unroll
      for (int r = 0; r < 8; ++r) redM[par][wave * 8 + r] = m[r];
    }
    __syncthreads();
    float M8[8];
#pragma unroll
    for (int r = 0; r < 8; ++r) {
      float a = fmaxf(redM[par][r], redM[par][8 + r]);
      float c = fmaxf(redM[par][16 + r], redM[par][24 + r]);
      M8[r] = fmaxf(fmaxf(a, c), lb_s[par][r]);
    }

    // ---- exp + block sum ----
    float e[8], s[8];
#pragma unroll
    for (int r = 0; r < 8; ++r) { e[r] = __expf(lg[r] - M8[r]); s[r] = e[r]; }
#pragma unroll
    for (int o = 32; o > 0; o >>= 1) {
#pragma unroll
      for (int r = 0; r < 8; ++r) s[r] += __shfl_down(s[r], o);
    }
    if (lane == 0) {
#pragma unroll
      for (int r = 0; r < 8; ++r) redS[par][wave * 8 + r] = s[r];
    }
    __syncthreads();

#pragma unroll
    for (int r = 0; r < 8; ++r) {
      int i = i0r + r;
      if (i < L_TOK) {
        float eb = __expf(lb_s[par][r] - M8[r]);
        float S = (redS[par][r] + redS[par][8 + r]) +
                  (redS[par][16 + r] + redS[par][24 + r]) + eb;
        float inv = 1.0f / S;
        Pb[(size_t)i * L_TOK + t] = e[r] * inv;
        if (t == r) Pb[(size_t)i * L_TOK + 256] = eb * inv;
      }
    }
  }
}

// ---------------- PV: out(L,N,C) = P(257x257) @ V(257x64) per head-batch ----------------
__global__ __launch_bounds__(256)
void pv_gemm(const float* __restrict__ P, const float* __restrict__ v,
             float* __restrict__ out_lnc) {
  __shared__ float Ps[64][65];
  __shared__ float Vs[64][65];
  const int b = blockIdx.y;
  const int n = b / N_H, h = b - n * N_H;
  const int i0 = blockIdx.x * 64;
  const int t = threadIdx.x;
  const int tm = t & 15, tn = t >> 4;
  const float* Pb = P + (size_t)b * L_TOK * L_TOK;
  const float* vb = v + (size_t)b * L_TOK * HD;
  float acc[4][4] = {};
  for (int k0 = 0; k0 < L_TOK; k0 += 64) {
    __syncthreads();
#pragma unroll
    for (int p = 0; p < 16; ++p) {
      int idx = p * 256 + t;
      int r = idx >> 6, c = idx & 63;
      float pv = 0.f;
      if (i0 + r < L_TOK && k0 + c < L_TOK)
        pv = Pb[(size_t)(i0 + r) * L_TOK + k0 + c];
      Ps[c][r] = pv;
      float vv = 0.f;
      if (k0 + r < L_TOK) vv = vb[(size_t)(k0 + r) * HD + c];
      Vs[r][c] = vv;
    }
    __syncthreads();
#pragma unroll 16
    for (int k = 0; k < 64; ++k) {
      float a0 = Ps[k][(tm << 2) + 0], a1 = Ps[k][(tm << 2) + 1];
      float a2 = Ps[k][(tm << 2) + 2], a3 = Ps[k][(tm << 2) + 3];
      float b0 = Vs[k][(tn << 2) + 0], b1 = Vs[k][(tn << 2) + 1];
      float b2 = Vs[k][(tn << 2) + 2], b3 = Vs[k][(tn << 2) + 3];
      acc[0][0] += a0 * b0; acc[0][1] += a0 * b1; acc[0][2] += a0 * b2; acc[0][3] += a0 * b3;
      acc[1][0] += a1 * b0; acc[1][1] += a1 * b1; acc[1][2] += a1 * b2; acc[1][3] += a1 * b3;
      acc[2][0] += a2 * b0; acc[2][1] += a2 * b1; acc[2][2] += a2 * b2; acc[2][3] += a2 * b3;
      acc[3][0] += a3 * b0; acc[3][1] += a3 * b1; acc[3][2] += a3 * b2; acc[3][3] += a3 * b3;
    }
  }
#pragma unroll
  for (int r = 0; r < 4; ++r) {
    int i = i0 + (tm << 2) + r;
    if (i < L_TOK) {
      size_t o = ((size_t)i * N_B + n) * C_DIM + h * HD + (tn << 2);
      *(float4*)(out_lnc + o) = make_float4(acc[r][0], acc[r][1], acc[r][2], acc[r][3]);
    }
  }
}

extern "C" void kernel_launch(void* const* d_in, const int* in_sizes, int n_in,
                              void* d_out, int out_size, void* d_ws, size_t ws_size,
                              hipStream_t stream) {
  const float* x      = (const float*)d_in[0];
  const float* depth  = (const float*)d_in[1];
  const float* w_in   = (const float*)d_in[2];
  const float* b_in   = (const float*)d_in[3];
  const float* w_out  = (const float*)d_in[4];
  const float* b_out  = (const float*)d_in[5];
  const float* rpe    = (const float*)d_in[6];
  const float* lscale = (const float*)d_in[7];
  float* out = (float*)d_out;
  float* ws = (float*)d_ws;

  float* qkv      = ws;                        // 18,948,096 floats
  float* attn_lnc = ws;                        // reused (first 6.3M floats)
  float* qn = ws + 18948096;                   // 6,316,032 each
  float* kn = qn + 6316032;
  float* v  = kn + 6316032;
  ushort* wsp = (ushort*)(v + 6316032);
  ushort* wihi = wsp;                          // 1,769,472
  ushort* wilo = wihi + 1769472;
  ushort* wohi = wilo + 1769472;               // 589,824
  ushort* wolo = wohi + 589824;
  ushort* xhi = (ushort*)qn;                   // overlay: dead before repack writes qn
  ushort* xlo = xhi + 6316032;
  ushort* ahi = (ushort*)(qkv + 6316032);      // overlay in qkv region past attn_lnc
  ushort* alo = ahi + 6316032;
  float* Pout = out + 6316032;

  cvt_split<<<6168, 256, 0, stream>>>(x, xhi, xlo, 6316032);
  cvt_split<<<1728, 256, 0, stream>>>(w_in, wihi, wilo, 1769472);
  cvt_split<<<576, 256, 0, stream>>>(w_out, wohi, wolo, 589824);

  gemm_mfma_split<<<dim3(65, 18), 256, 0, stream>>>(xhi, xlo, wihi, wilo, b_in, qkv,
                                                    M_TOK, 3 * C_DIM, C_DIM);
  repack_norm<<<24672, 256, 0, stream>>>(qkv, qn, kn, v);
  attn_rows<<<dim3(4, BH), 256, 0, stream>>>(qn, kn, depth, rpe, lscale, Pout);
  pv_gemm<<<dim3(5, BH), 256, 0, stream>>>(Pout, v, attn_lnc);

  cvt_split<<<6168, 256, 0, stream>>>(attn_lnc, ahi, alo, 6316032);
  gemm_mfma_split<<<dim3(65, 6), 256, 0, stream>>>(ahi, alo, wohi, wolo, b_out, out,
                                                   M_TOK, C_DIM, C_DIM);
}

// Round 4
// 597.021 us; speedup vs baseline: 2.2276x; 1.3798x over previous
//
#include <hip/hip_runtime.h>
#include <math.h>

#define L_TOK 257
#define N_B 32
#define C_DIM 768
#define N_H 12
#define HD 64
#define BH (N_B * N_H)          /* 384 */
#define M_TOK (L_TOK * N_B)     /* 8224 */
#define HW 256
#define RPE_NUM 33
#define LOGIT_MAX 4.6051701859880913680f

typedef unsigned short ushort;
typedef unsigned int uint;
typedef __attribute__((ext_vector_type(8))) short short8;
typedef __attribute__((ext_vector_type(4))) float f32x4;

__device__ __forceinline__ ushort f2bf_rn(float f) {
  uint u = __float_as_uint(f);
  uint r = (u + 0x7FFF + ((u >> 16) & 1)) >> 16;
  return (ushort)r;
}
__device__ __forceinline__ float bf2f(ushort h) {
  return __uint_as_float(((uint)h) << 16);
}

// ---------------- fp32 -> bf16 hi/lo split ----------------
__global__ __launch_bounds__(256)
void cvt_split(const float* __restrict__ src, ushort* __restrict__ hi,
               ushort* __restrict__ lo, int n) {
  int i = (blockIdx.x * 256 + threadIdx.x) * 4;
  if (i + 3 >= n + 3) return;
  if (i + 3 < n) {
    float4 v = *(const float4*)(src + i);
    ushort h0 = f2bf_rn(v.x), h1 = f2bf_rn(v.y), h2 = f2bf_rn(v.z), h3 = f2bf_rn(v.w);
    ushort l0 = f2bf_rn(v.x - bf2f(h0)), l1 = f2bf_rn(v.y - bf2f(h1));
    ushort l2 = f2bf_rn(v.z - bf2f(h2)), l3 = f2bf_rn(v.w - bf2f(h3));
    *(ushort4*)(hi + i) = make_ushort4(h0, h1, h2, h3);
    *(ushort4*)(lo + i) = make_ushort4(l0, l1, l2, l3);
  } else {
    for (int k = i; k < n; ++k) {
      float vv = src[k];
      ushort h = f2bf_rn(vv);
      hi[k] = h; lo[k] = f2bf_rn(vv - bf2f(h));
    }
  }
}

// ---------------- split-bf16 MFMA GEMM: C[M][Nn] = A[M][K] @ W[Nn][K]^T + bias ----------------
__global__ __launch_bounds__(256)
void gemm_mfma_split(const ushort* __restrict__ Ahi, const ushort* __restrict__ Alo,
                     const ushort* __restrict__ Bhi, const ushort* __restrict__ Blo,
                     const float* __restrict__ bias, float* __restrict__ Cout,
                     int M, int Nn, int K) {
  __shared__ __align__(16) ushort lds[4 * 128 * 32];   // 32 KB
  ushort* sAh = lds;
  ushort* sAl = lds + 4096;
  ushort* sBh = lds + 8192;
  ushort* sBl = lds + 12288;

  const int t = threadIdx.x;
  const int wave = t >> 6, lane = t & 63;
  const int wm = (wave & 1) * 64;
  const int wn = (wave >> 1) * 64;
  const int m0 = blockIdx.x * 128;
  const int n0 = blockIdx.y * 128;

  const int ar = t >> 2;
  const int ac = (t & 3) * 8;
  const uint ldsOff = (uint)(t & 192) * 16;

  const int frm = lane & 15;
  const int frk = (lane >> 4) * 8;

  f32x4 acc[4][4] = {};

  for (int k0 = 0; k0 < K; k0 += 32) {
#pragma unroll
    for (int half = 0; half < 2; ++half) {
      int rA = m0 + half * 64 + ar; if (rA > M - 1) rA = M - 1;
      int rB = n0 + half * 64 + ar;
      size_t gA = (size_t)rA * K + k0 + ac;
      size_t gB = (size_t)rB * K + k0 + ac;
      uint so = (uint)half * 4096 + ldsOff;
      __builtin_amdgcn_global_load_lds(
          (const __attribute__((address_space(1))) void*)(Ahi + gA),
          (__attribute__((address_space(3))) void*)((char*)sAh + so), 16, 0, 0);
      __builtin_amdgcn_global_load_lds(
          (const __attribute__((address_space(1))) void*)(Alo + gA),
          (__attribute__((address_space(3))) void*)((char*)sAl + so), 16, 0, 0);
      __builtin_amdgcn_global_load_lds(
          (const __attribute__((address_space(1))) void*)(Bhi + gB),
          (__attribute__((address_space(3))) void*)((char*)sBh + so), 16, 0, 0);
      __builtin_amdgcn_global_load_lds(
          (const __attribute__((address_space(1))) void*)(Blo + gB),
          (__attribute__((address_space(3))) void*)((char*)sBl + so), 16, 0, 0);
    }
    __syncthreads();

    short8 ah[4], al[4], bh[4], bl[4];
#pragma unroll
    for (int i = 0; i < 4; ++i) {
      int r = wm + i * 16 + frm;
      ah[i] = *(const short8*)(sAh + r * 32 + frk);
      al[i] = *(const short8*)(sAl + r * 32 + frk);
      int c = wn + i * 16 + frm;
      bh[i] = *(const short8*)(sBh + c * 32 + frk);
      bl[i] = *(const short8*)(sBl + c * 32 + frk);
    }
#pragma unroll
    for (int i = 0; i < 4; ++i)
#pragma unroll
      for (int j = 0; j < 4; ++j) {
        acc[i][j] = __builtin_amdgcn_mfma_f32_16x16x32_bf16(ah[i], bh[j], acc[i][j], 0, 0, 0);
        acc[i][j] = __builtin_amdgcn_mfma_f32_16x16x32_bf16(ah[i], bl[j], acc[i][j], 0, 0, 0);
        acc[i][j] = __builtin_amdgcn_mfma_f32_16x16x32_bf16(al[i], bh[j], acc[i][j], 0, 0, 0);
      }
    __syncthreads();
  }

  const int ecol = lane & 15;
#pragma unroll
  for (int j = 0; j < 4; ++j) {
    int col = n0 + wn + j * 16 + ecol;
    float bv = bias[col];
#pragma unroll
    for (int i = 0; i < 4; ++i) {
      int rbase = m0 + wm + i * 16 + (lane >> 4) * 4;
#pragma unroll
      for (int r = 0; r < 4; ++r) {
        int row = rbase + r;
        if (row < M) Cout[(size_t)row * Nn + col] = acc[i][j][r] + bv;
      }
    }
  }
}

// ---------------- repack qkv -> q/k bf16 hi/lo splits + v fp32, [b][l][64] ----------------
__global__ __launch_bounds__(256)
void repack_norm(const float* __restrict__ qkv,
                 ushort* __restrict__ qhi, ushort* __restrict__ qlo,
                 ushort* __restrict__ khi, ushort* __restrict__ klo,
                 float* __restrict__ v) {
  int gw = blockIdx.x * 4 + (threadIdx.x >> 6);
  int lane = threadIdx.x & 63;
  int b = gw / L_TOK, l = gw - b * L_TOK;
  int n = b / N_H, h = b - n * N_H;
  size_t base = (size_t)(l * N_B + n) * (3 * C_DIM) + h * HD + lane;
  float q = qkv[base];
  float k = qkv[base + C_DIM];
  float vv = qkv[base + 2 * C_DIM];
  float sq = q * q, sk = k * k;
#pragma unroll
  for (int o = 32; o > 0; o >>= 1) {
    sq += __shfl_down(sq, o);
    sk += __shfl_down(sk, o);
  }
  sq = __shfl(sq, 0);
  sk = __shfl(sk, 0);
  float iq = 1.0f / fmaxf(sqrtf(sq), 1e-12f);
  float ik = 1.0f / fmaxf(sqrtf(sk), 1e-12f);
  float qn_ = q * iq, kn_ = k * ik;
  size_t ob = (size_t)(b * L_TOK + l) * HD + lane;
  ushort qh = f2bf_rn(qn_);
  qhi[ob] = qh; qlo[ob] = f2bf_rn(qn_ - bf2f(qh));
  ushort kh = f2bf_rn(kn_);
  khi[ob] = kh; klo[ob] = f2bf_rn(kn_ - bf2f(kh));
  v[ob] = vv;
}

// ---------------- MFMA attention: rows 0..255, all 257 cols, softmax -> P ----------------
__global__ __launch_bounds__(256)
void attn_mfma(const ushort* __restrict__ qhi, const ushort* __restrict__ qlo,
               const ushort* __restrict__ khi, const ushort* __restrict__ klo,
               const float* __restrict__ depth, const float* __restrict__ rpe,
               const float* __restrict__ lscale, float* __restrict__ P) {
  __shared__ __align__(16) ushort sKh[256 * 72];   // 36,864 B
  __shared__ __align__(16) ushort sKl[256 * 72];
  __shared__ float cz_s[HW];
  __shared__ float txd[32], tyd[32], tzt[36];
  __shared__ float red_s[16];
  __shared__ float s256[4][16];

  const int tile = blockIdx.x;             // 0..3 -> rows tile*64..tile*64+63
  const int b = blockIdx.y;
  const int n = b / N_H, h = b - n * N_H;
  const int t = threadIdx.x;
  const int lane = t & 63, wave = t >> 6;

  // depth -> cz (bit-exact op sequence vs reference)
  float dval = depth[n * HW + t];
  float mn = dval, mx = dval;
#pragma unroll
  for (int o = 32; o > 0; o >>= 1) {
    mn = fminf(mn, __shfl_down(mn, o));
    mx = fmaxf(mx, __shfl_down(mx, o));
  }
  if (lane == 0) { red_s[wave] = mn; red_s[8 + wave] = mx; }
  __syncthreads();
  float zmin = fminf(fminf(red_s[0], red_s[1]), fminf(red_s[2], red_s[3]));
  float zmax = fmaxf(fmaxf(red_s[8], red_s[9]), fmaxf(red_s[10], red_s[11]));
  float den = zmax - zmin + 1e-8f;
  cz_s[t] = (dval - zmin) / den;
  if (t < 31) {
    int d = t - 15;
    int ix = (int)rintf((float)d * (16.0f / 15.0f));
    ix = max(-16, min(16, ix));
    txd[t] = rpe[(ix + 16) * N_H + h];
    tyd[t] = rpe[(RPE_NUM + ix + 16) * N_H + h];
  }
  if (t < RPE_NUM) tzt[t] = rpe[(2 * RPE_NUM + t) * N_H + h];
  const float scale = expf(fminf(lscale[h], LOGIT_MAX));

  // stage K rows 0..255 (bf16 hi/lo), LDS stride 72 ushorts
  const ushort* khb = khi + (size_t)b * L_TOK * HD;
  const ushort* klb = klo + (size_t)b * L_TOK * HD;
#pragma unroll
  for (int it = 0; it < 8; ++it) {
    int idx = it * 256 + t;
    int j = idx >> 3, c = (idx & 7) * 8;
    *(uint4*)(sKh + j * 72 + c) = *(const uint4*)(khb + (size_t)j * HD + c);
    *(uint4*)(sKl + j * 72 + c) = *(const uint4*)(klb + (size_t)j * HD + c);
  }
  __syncthreads();

  // Q A-frags direct from global (A[m=lane&15][k=(lane>>4)*8+j])
  const int qrow = tile * 64 + 16 * wave;
  const size_t qoff = ((size_t)b * L_TOK + qrow + (lane & 15)) * HD + (lane >> 4) * 8;
  short8 qh0 = *(const short8*)(qhi + qoff);
  short8 qh1 = *(const short8*)(qhi + qoff + 32);
  short8 ql0 = *(const short8*)(qlo + qoff);
  short8 ql1 = *(const short8*)(qlo + qoff + 32);

  f32x4 acc[16] = {};
#pragma unroll
  for (int jt = 0; jt < 16; ++jt) {
    const ushort* bp = sKh + (jt * 16 + (lane & 15)) * 72 + (lane >> 4) * 8;
    const ushort* bq = sKl + (jt * 16 + (lane & 15)) * 72 + (lane >> 4) * 8;
    short8 bh0 = *(const short8*)(bp);
    short8 bh1 = *(const short8*)(bp + 32);
    short8 bl0 = *(const short8*)(bq);
    short8 bl1 = *(const short8*)(bq + 32);
    acc[jt] = __builtin_amdgcn_mfma_f32_16x16x32_bf16(qh0, bh0, acc[jt], 0, 0, 0);
    acc[jt] = __builtin_amdgcn_mfma_f32_16x16x32_bf16(qh1, bh1, acc[jt], 0, 0, 0);
    acc[jt] = __builtin_amdgcn_mfma_f32_16x16x32_bf16(qh0, bl0, acc[jt], 0, 0, 0);
    acc[jt] = __builtin_amdgcn_mfma_f32_16x16x32_bf16(qh1, bl1, acc[jt], 0, 0, 0);
    acc[jt] = __builtin_amdgcn_mfma_f32_16x16x32_bf16(ql0, bh0, acc[jt], 0, 0, 0);
    acc[jt] = __builtin_amdgcn_mfma_f32_16x16x32_bf16(ql1, bh1, acc[jt], 0, 0, 0);
  }

  // col-256 dots via the Q frags (fp32 reconstruct), xor-reduce over k-groups
  {
    const ushort* k6h = khb + (size_t)256 * HD + (lane >> 4) * 8;
    const ushort* k6l = klb + (size_t)256 * HD + (lane >> 4) * 8;
    float p = 0.f;
#pragma unroll
    for (int j = 0; j < 8; ++j) {
      float kf0 = bf2f(k6h[j]) + bf2f(k6l[j]);
      float kf1 = bf2f(k6h[32 + j]) + bf2f(k6l[32 + j]);
      float qf0 = bf2f((ushort)qh0[j]) + bf2f((ushort)ql0[j]);
      float qf1 = bf2f((ushort)qh1[j]) + bf2f((ushort)ql1[j]);
      p = fmaf(qf0, kf0, fmaf(qf1, kf1, p));
    }
    p += __shfl_xor(p, 16);
    p += __shfl_xor(p, 32);
    if (lane < 16) s256[wave][lane] = p;
  }

  const int g = lane >> 4, c0 = lane & 15;

  // col-256 logits (uniform within 16-lane group)
  float lg6[4];
#pragma unroll
  for (int r = 0; r < 4; ++r) {
    int gi = tile * 64 + 16 * wave + 4 * g + r;
    float d6 = s256[wave][4 * g + r];
    float bz = 0.f;
    if (gi >= 1) {
      int dx = ((gi - 1) & 15) - 15;
      int dy = ((gi - 1) >> 4) - 15;
      float rz = (cz_s[gi - 1] - cz_s[255]) * 16.0f;
      int iz = (int)rintf(rz); iz = max(-16, min(16, iz));
      bz = txd[dx + 15] + tyd[dy + 15] + tzt[iz + 16];
    }
    lg6[r] = scale * d6 + bz;
  }

  // bias -> logits in place
#pragma unroll
  for (int jt = 0; jt < 16; ++jt) {
    int col = jt * 16 + c0;
#pragma unroll
    for (int r = 0; r < 4; ++r) {
      int gi = tile * 64 + 16 * wave + 4 * g + r;
      float lv = scale * acc[jt][r];
      if (col >= 1 && gi >= 1) {
        int dx = ((gi - 1) & 15) - ((col - 1) & 15);
        int dy = ((gi - 1) >> 4) - ((col - 1) >> 4);
        float rz = (cz_s[gi - 1] - cz_s[col - 1]) * 16.0f;
        int iz = (int)rintf(rz); iz = max(-16, min(16, iz));
        lv += txd[dx + 15] + tyd[dy + 15] + tzt[iz + 16];
      }
      acc[jt][r] = lv;
    }
  }

  // softmax per row (rows live in (g,r); reduce across low-4 lane bits)
  float* Pb_ = P + (size_t)b * L_TOK * L_TOK;
#pragma unroll
  for (int r = 0; r < 4; ++r) {
    int gi = tile * 64 + 16 * wave + 4 * g + r;
    float m = acc[0][r];
#pragma unroll
    for (int jt = 1; jt < 16; ++jt) m = fmaxf(m, acc[jt][r]);
#pragma unroll
    for (int o = 1; o < 16; o <<= 1) m = fmaxf(m, __shfl_xor(m, o));
    m = fmaxf(m, lg6[r]);
    float s = 0.f;
#pragma unroll
    for (int jt = 0; jt < 16; ++jt) {
      float e = __expf(acc[jt][r] - m);
      acc[jt][r] = e;
      s += e;
    }
#pragma unroll
    for (int o = 1; o < 16; o <<= 1) s += __shfl_xor(s, o);
    float e6 = __expf(lg6[r] - m);
    float inv = 1.0f / (s + e6);
    float* Prow = Pb_ + (size_t)gi * L_TOK;
#pragma unroll
    for (int jt = 0; jt < 16; ++jt)
      Prow[jt * 16 + c0] = acc[jt][r] * inv;
    if (c0 == 0) Prow[256] = e6 * inv;
  }
}

// ---------------- row 256: plain VALU dot + softmax ----------------
__global__ __launch_bounds__(256)
void attn_row256(const ushort* __restrict__ qhi, const ushort* __restrict__ qlo,
                 const ushort* __restrict__ khi, const ushort* __restrict__ klo,
                 const float* __restrict__ depth, const float* __restrict__ rpe,
                 const float* __restrict__ lscale, float* __restrict__ P) {
  __shared__ float qs[HD];
  __shared__ float cz_s[HW];
  __shared__ float txd[32], tyd[32], tzt[36];
  __shared__ float red_s[16];
  __shared__ float lg6_sh;

  const int b = blockIdx.x;
  const int n = b / N_H, h = b - n * N_H;
  const int t = threadIdx.x;
  const int lane = t & 63, wave = t >> 6;

  float dval = depth[n * HW + t];
  float mn = dval, mx = dval;
#pragma unroll
  for (int o = 32; o > 0; o >>= 1) {
    mn = fminf(mn, __shfl_down(mn, o));
    mx = fmaxf(mx, __shfl_down(mx, o));
  }
  if (lane == 0) { red_s[wave] = mn; red_s[8 + wave] = mx; }
  __syncthreads();
  float zmin = fminf(fminf(red_s[0], red_s[1]), fminf(red_s[2], red_s[3]));
  float zmax = fmaxf(fmaxf(red_s[8], red_s[9]), fmaxf(red_s[10], red_s[11]));
  float den = zmax - zmin + 1e-8f;
  cz_s[t] = (dval - zmin) / den;
  if (t < 31) {
    int d = t - 15;
    int ix = (int)rintf((float)d * (16.0f / 15.0f));
    ix = max(-16, min(16, ix));
    txd[t] = rpe[(ix + 16) * N_H + h];
    tyd[t] = rpe[(RPE_NUM + ix + 16) * N_H + h];
  }
  if (t < RPE_NUM) tzt[t] = rpe[(2 * RPE_NUM + t) * N_H + h];
  const float scale = expf(fminf(lscale[h], LOGIT_MAX));

  const size_t q6 = ((size_t)b * L_TOK + 256) * HD;
  if (t < HD) qs[t] = bf2f(qhi[q6 + t]) + bf2f(qlo[q6 + t]);
  __syncthreads();

  // key j = t
  const ushort* krh = khi + ((size_t)b * L_TOK + t) * HD;
  const ushort* krl = klo + ((size_t)b * L_TOK + t) * HD;
  float dot = 0.f;
#pragma unroll
  for (int c = 0; c < HD; c += 8) {
    ushort4 hv0 = *(const ushort4*)(krh + c);
    ushort4 hv1 = *(const ushort4*)(krh + c + 4);
    ushort4 lv0 = *(const ushort4*)(krl + c);
    ushort4 lv1 = *(const ushort4*)(krl + c + 4);
    dot = fmaf(bf2f(hv0.x) + bf2f(lv0.x), qs[c + 0], dot);
    dot = fmaf(bf2f(hv0.y) + bf2f(lv0.y), qs[c + 1], dot);
    dot = fmaf(bf2f(hv0.z) + bf2f(lv0.z), qs[c + 2], dot);
    dot = fmaf(bf2f(hv0.w) + bf2f(lv0.w), qs[c + 3], dot);
    dot = fmaf(bf2f(hv1.x) + bf2f(lv1.x), qs[c + 4], dot);
    dot = fmaf(bf2f(hv1.y) + bf2f(lv1.y), qs[c + 5], dot);
    dot = fmaf(bf2f(hv1.z) + bf2f(lv1.z), qs[c + 6], dot);
    dot = fmaf(bf2f(hv1.w) + bf2f(lv1.w), qs[c + 7], dot);
  }

  float lg;
  {
    float bsum = 0.f;
    if (t >= 1) {
      int dx = 15 - ((t - 1) & 15);
      int dy = 15 - ((t - 1) >> 4);
      float rz = (cz_s[255] - cz_s[t - 1]) * 16.0f;
      int iz = (int)rintf(rz); iz = max(-16, min(16, iz));
      bsum = txd[dx + 15] + tyd[dy + 15] + tzt[iz + 16];
    }
    lg = scale * dot + bsum;
  }

  // key 256 by wave 0
  if (wave == 0) {
    const ushort* k6h = khi + q6;
    const ushort* k6l = klo + q6;
    float pp = (bf2f(k6h[lane]) + bf2f(k6l[lane])) * qs[lane];
#pragma unroll
    for (int o = 32; o > 0; o >>= 1) pp += __shfl_down(pp, o);
    if (lane == 0) {
      // bias(256,256): dx=dy=0, rz=0 -> iz=0
      float bz = txd[15] + tyd[15] + tzt[16];
      lg6_sh = scale * pp + bz;
    }
  }

  // block softmax over 257
  float m = lg;
#pragma unroll
  for (int o = 32; o > 0; o >>= 1) m = fmaxf(m, __shfl_down(m, o));
  if (lane == 0) red_s[wave] = m;
  __syncthreads();
  float M = fmaxf(fmaxf(red_s[0], red_s[1]), fmaxf(red_s[2], red_s[3]));
  M = fmaxf(M, lg6_sh);
  float e = __expf(lg - M);
  float s = e;
#pragma unroll
  for (int o = 32; o > 0; o >>= 1) s += __shfl_down(s, o);
  if (lane == 0) red_s[8 + wave] = s;
  __syncthreads();
  float e6 = __expf(lg6_sh - M);
  float S = (red_s[8] + red_s[9]) + (red_s[10] + red_s[11]) + e6;
  float inv = 1.0f / S;
  float* Prow = P + (size_t)b * L_TOK * L_TOK + (size_t)256 * L_TOK;
  Prow[t] = e * inv;
  if (t == 0) Prow[256] = e6 * inv;
}

// ---------------- PV: out(L,N,C) = P(257x257) @ V(257x64) per head-batch ----------------
__global__ __launch_bounds__(256)
void pv_gemm(const float* __restrict__ P, const float* __restrict__ v,
             float* __restrict__ out_lnc) {
  __shared__ float Ps[64][65];
  __shared__ float Vs[64][65];
  const int b = blockIdx.y;
  const int n = b / N_H, h = b - n * N_H;
  const int i0 = blockIdx.x * 64;
  const int t = threadIdx.x;
  const int tm = t & 15, tn = t >> 4;
  const float* Pb = P + (size_t)b * L_TOK * L_TOK;
  const float* vb = v + (size_t)b * L_TOK * HD;
  float acc[4][4] = {};
  for (int k0 = 0; k0 < L_TOK; k0 += 64) {
    __syncthreads();
#pragma unroll
    for (int p = 0; p < 16; ++p) {
      int idx = p * 256 + t;
      int r = idx >> 6, c = idx & 63;
      float pv = 0.f;
      if (i0 + r < L_TOK && k0 + c < L_TOK)
        pv = Pb[(size_t)(i0 + r) * L_TOK + k0 + c];
      Ps[c][r] = pv;
      float vv = 0.f;
      if (k0 + r < L_TOK) vv = vb[(size_t)(k0 + r) * HD + c];
      Vs[r][c] = vv;
    }
    __syncthreads();
#pragma unroll 16
    for (int k = 0; k < 64; ++k) {
      float a0 = Ps[k][(tm << 2) + 0], a1 = Ps[k][(tm << 2) + 1];
      float a2 = Ps[k][(tm << 2) + 2], a3 = Ps[k][(tm << 2) + 3];
      float b0 = Vs[k][(tn << 2) + 0], b1 = Vs[k][(tn << 2) + 1];
      float b2 = Vs[k][(tn << 2) + 2], b3 = Vs[k][(tn << 2) + 3];
      acc[0][0] += a0 * b0; acc[0][1] += a0 * b1; acc[0][2] += a0 * b2; acc[0][3] += a0 * b3;
      acc[1][0] += a1 * b0; acc[1][1] += a1 * b1; acc[1][2] += a1 * b2; acc[1][3] += a1 * b3;
      acc[2][0] += a2 * b0; acc[2][1] += a2 * b1; acc[2][2] += a2 * b2; acc[2][3] += a2 * b3;
      acc[3][0] += a3 * b0; acc[3][1] += a3 * b1; acc[3][2] += a3 * b2; acc[3][3] += a3 * b3;
    }
  }
#pragma unroll
  for (int r = 0; r < 4; ++r) {
    int i = i0 + (tm << 2) + r;
    if (i < L_TOK) {
      size_t o = ((size_t)i * N_B + n) * C_DIM + h * HD + (tn << 2);
      *(float4*)(out_lnc + o) = make_float4(acc[r][0], acc[r][1], acc[r][2], acc[r][3]);
    }
  }
}

extern "C" void kernel_launch(void* const* d_in, const int* in_sizes, int n_in,
                              void* d_out, int out_size, void* d_ws, size_t ws_size,
                              hipStream_t stream) {
  const float* x      = (const float*)d_in[0];
  const float* depth  = (const float*)d_in[1];
  const float* w_in   = (const float*)d_in[2];
  const float* b_in   = (const float*)d_in[3];
  const float* w_out  = (const float*)d_in[4];
  const float* b_out  = (const float*)d_in[5];
  const float* rpe    = (const float*)d_in[6];
  const float* lscale = (const float*)d_in[7];
  float* out = (float*)d_out;
  float* ws = (float*)d_ws;

  // layout (float units)
  float* qkv      = ws;                         // 18,948,096
  float* attn_lnc = ws;                         // reuse first 6,316,032
  float* v        = ws + 18948096;              // 6,316,032
  ushort* qhi = (ushort*)(ws + 25264128);       // 6,316,032 ushorts each
  ushort* qlo = qhi + 6316032;
  ushort* khi = qlo + 6316032;
  ushort* klo = khi + 6316032;
  ushort* wihi = (ushort*)(ws + 37896192);      // 1,769,472
  ushort* wilo = wihi + 1769472;
  ushort* wohi = wilo + 1769472;                // 589,824
  ushort* wolo = wohi + 589824;
  ushort* xhi = qhi;                            // overlay: dead before repack writes
  ushort* xlo = qlo;
  ushort* ahi = (ushort*)(qkv + 6316032);       // overlay past attn_lnc
  ushort* alo = ahi + 6316032;
  float* Pout = out + 6316032;

  cvt_split<<<6168, 256, 0, stream>>>(x, xhi, xlo, 6316032);
  cvt_split<<<1728, 256, 0, stream>>>(w_in, wihi, wilo, 1769472);
  cvt_split<<<576, 256, 0, stream>>>(w_out, wohi, wolo, 589824);

  gemm_mfma_split<<<dim3(65, 18), 256, 0, stream>>>(xhi, xlo, wihi, wilo, b_in, qkv,
                                                    M_TOK, 3 * C_DIM, C_DIM);
  repack_norm<<<24672, 256, 0, stream>>>(qkv, qhi, qlo, khi, klo, v);
  attn_mfma<<<dim3(4, BH), 256, 0, stream>>>(qhi, qlo, khi, klo, depth, rpe, lscale, Pout);
  attn_row256<<<BH, 256, 0, stream>>>(qhi, qlo, khi, klo, depth, rpe, lscale, Pout);
  pv_gemm<<<dim3(5, BH), 256, 0, stream>>>(Pout, v, attn_lnc);

  cvt_split<<<6168, 256, 0, stream>>>(attn_lnc, ahi, alo, 6316032);
  gemm_mfma_split<<<dim3(65, 6), 256, 0, stream>>>(ahi, alo, wohi, wolo, b_out, out,
                                                   M_TOK, C_DIM, C_DIM);
}